// Round 5
// baseline (979.337 us; speedup 1.0000x reference)
//
#include <hip/hip_runtime.h>
#include <math.h>

// ---------------------------------------------------------------------------
// VisionMambaDenoiser. Round 5: decoder GEMM coalesced LDS-staged stores +
// 2-batch dispatches; conv k-split (6 blocks/CU); scan 32-chunks.
// ---------------------------------------------------------------------------

typedef short bf16x8 __attribute__((ext_vector_type(8)));
typedef float f32x4 __attribute__((ext_vector_type(4)));

__device__ inline unsigned short f2bf(float f) {
    unsigned int u = __float_as_uint(f);
    unsigned int r = (u + 0x7fff + ((u >> 16) & 1)) >> 16;   // RNE
    return (unsigned short)r;
}

// ---------------- flexible bf16 MFMA GEMM: C = A @ W^T (+bias) --------------
// A (M,K) bf16 row-major, W (N,K) bf16. M%128==0, K%32==0, N guarded.
__global__ __launch_bounds__(256) void gemm_mfma_flex(
    const unsigned short* __restrict__ A, const unsigned short* __restrict__ W,
    void* __restrict__ Cout, const float* __restrict__ bias,
    int M, int N, int K, int out_bf16)
{
    __shared__ unsigned short As[128][48];
    __shared__ unsigned short Bs[128][48];
    const int tid = threadIdx.x;
    const int wave = tid >> 6, lane = tid & 63;
    const int wm = (wave & 1) * 64, wn = (wave >> 1) * 64;
    const int m0 = blockIdx.y * 128, n0 = blockIdx.x * 128;
    const int quad = lane >> 4, lr = lane & 15;
    const uint4 z4 = {0, 0, 0, 0};

    f32x4 acc[4][4];
    #pragma unroll
    for (int i = 0; i < 4; ++i)
        #pragma unroll
        for (int j = 0; j < 4; ++j)
            acc[i][j] = (f32x4){0.f, 0.f, 0.f, 0.f};

    const int r = tid >> 2, kq = tid & 3;
    for (int k0 = 0; k0 < K; k0 += 32) {
        #pragma unroll
        for (int half = 0; half < 2; ++half) {
            int rr = r + half * 64;
            *(uint4*)(&As[rr][kq * 8]) =
                *(const uint4*)(A + (size_t)(m0 + rr) * K + k0 + kq * 8);
            uint4 bv = z4;
            if (n0 + rr < N)
                bv = *(const uint4*)(W + (size_t)(n0 + rr) * K + k0 + kq * 8);
            *(uint4*)(&Bs[rr][kq * 8]) = bv;
        }
        __syncthreads();
        bf16x8 af[4], bfr[4];
        #pragma unroll
        for (int i = 0; i < 4; ++i) af[i] = *(const bf16x8*)(&As[wm + i * 16 + lr][quad * 8]);
        #pragma unroll
        for (int j = 0; j < 4; ++j) bfr[j] = *(const bf16x8*)(&Bs[wn + j * 16 + lr][quad * 8]);
        #pragma unroll
        for (int i = 0; i < 4; ++i)
            #pragma unroll
            for (int j = 0; j < 4; ++j)
                acc[i][j] = __builtin_amdgcn_mfma_f32_16x16x32_bf16(af[i], bfr[j], acc[i][j], 0, 0, 0);
        __syncthreads();
    }

    #pragma unroll
    for (int i = 0; i < 4; ++i) {
        int gm = m0 + wm + i * 16 + quad * 4;
        #pragma unroll
        for (int j = 0; j < 4; ++j) {
            int gn = n0 + wn + j * 16 + lr;
            if (gn >= N) continue;
            float bv = bias ? bias[gn] : 0.f;
            #pragma unroll
            for (int rr = 0; rr < 4; ++rr) {
                float v = acc[i][j][rr] + bv;
                if (out_bf16) ((unsigned short*)Cout)[(size_t)(gm + rr) * N + gn] = f2bf(v);
                else          ((float*)Cout)[(size_t)(gm + rr) * N + gn] = v;
            }
        }
    }
}

// ---------------- decoder MFMA GEMM (2 batches): Db=bf16(relu(A@W^T+b)) -----
// Coalesced epilogue: C-tile staged in LDS, dwordx4 stores.
__global__ __launch_bounds__(256) void gemm_mfma_relu_bf16(
    const unsigned short* __restrict__ A0, const unsigned short* __restrict__ W,
    unsigned short* __restrict__ C0, const float* __restrict__ bias, int pair)
{
    __shared__ unsigned short smem[12288];       // As | Bs, reused as Ct
    unsigned short* As = smem;                   // [128][48]
    unsigned short* Bs = smem + 6144;            // [128][48]
    const int N = 16384, K = 192;
    const int tid = threadIdx.x;
    const int wave = tid >> 6, lane = tid & 63;
    const int wm = (wave & 1) * 64, wn = (wave >> 1) * 64;
    const int m0 = blockIdx.y * 128, n0 = blockIdx.x * 128;
    const int z = blockIdx.z;
    const unsigned short* A = A0 + (size_t)(pair * 2 + z) * 1024 * 192;
    unsigned short* C = C0 + (size_t)z * 16777216;
    const int quad = lane >> 4, lr = lane & 15;

    f32x4 acc[4][4];
    #pragma unroll
    for (int i = 0; i < 4; ++i)
        #pragma unroll
        for (int j = 0; j < 4; ++j)
            acc[i][j] = (f32x4){0.f, 0.f, 0.f, 0.f};

    const int r = tid >> 2, kq = tid & 3;
    for (int k0 = 0; k0 < K; k0 += 32) {
        #pragma unroll
        for (int half = 0; half < 2; ++half) {
            int rr = r + half * 64;
            *(uint4*)(&As[rr * 48 + kq * 8]) =
                *(const uint4*)(A + (size_t)(m0 + rr) * K + k0 + kq * 8);
            *(uint4*)(&Bs[rr * 48 + kq * 8]) =
                *(const uint4*)(W + (size_t)(n0 + rr) * K + k0 + kq * 8);
        }
        __syncthreads();
        bf16x8 af[4], bfr[4];
        #pragma unroll
        for (int i = 0; i < 4; ++i) af[i] = *(const bf16x8*)(&As[(wm + i * 16 + lr) * 48 + quad * 8]);
        #pragma unroll
        for (int j = 0; j < 4; ++j) bfr[j] = *(const bf16x8*)(&Bs[(wn + j * 16 + lr) * 48 + quad * 8]);
        #pragma unroll
        for (int i = 0; i < 4; ++i)
            #pragma unroll
            for (int j = 0; j < 4; ++j)
                acc[i][j] = __builtin_amdgcn_mfma_f32_16x16x32_bf16(af[i], bfr[j], acc[i][j], 0, 0, 0);
        __syncthreads();
    }

    // epilogue: two 64-row halves through LDS (row stride 136), coalesced out
    unsigned short* Ct = smem;                   // 64*136 = 8704 <= 12288
    #pragma unroll
    for (int h = 0; h < 2; ++h) {
        if ((wave & 1) == h) {
            #pragma unroll
            for (int i = 0; i < 4; ++i) {
                int lrow = i * 16 + quad * 4;
                #pragma unroll
                for (int j = 0; j < 4; ++j) {
                    int lcol = wn + j * 16 + lr;
                    float bv = bias[(n0 + lcol) & 63];
                    #pragma unroll
                    for (int rr = 0; rr < 4; ++rr) {
                        float v = fmaxf(acc[i][j][rr] + bv, 0.f);
                        Ct[(lrow + rr) * 136 + lcol] = f2bf(v);
                    }
                }
            }
        }
        __syncthreads();
        #pragma unroll
        for (int p = 0; p < 4; ++p) {
            int idx = p * 256 + tid;             // 0..1023
            int row = idx >> 4, cg = idx & 15;
            *(uint4*)(C + (size_t)(m0 + h * 64 + row) * N + n0 + cg * 8) =
                *(const uint4*)(&Ct[row * 136 + cg * 8]);
        }
        __syncthreads();
    }
}

// ---------------- im2col of 16x16 patches -> bf16 ---------------------------
__global__ __launch_bounds__(256) void im2col_bf16(const float* __restrict__ x,
                                                   unsigned short* __restrict__ P)
{
    int idx = blockIdx.x * 256 + threadIdx.x;   // 8192*768
    int col = idx % 768;
    int row = idx / 768;
    int b = row >> 10;
    int l = row & 1023;
    int h = l >> 5, w = l & 31;
    int c = col >> 8;
    int p = (col >> 4) & 15, q = col & 15;
    P[idx] = f2bf(x[((size_t)(b * 3 + c) * 512 + (h * 16 + p)) * 512 + (w * 16 + q)]);
}

// ---------------- fused fp32 -> bf16 weight converts ------------------------
__global__ __launch_bounds__(256) void f2b_all(
    const float* __restrict__ a, unsigned short* __restrict__ da,
    const float* __restrict__ b, unsigned short* __restrict__ db,
    const float* __restrict__ c, unsigned short* __restrict__ dc,
    const float* __restrict__ d, unsigned short* __restrict__ dd)
{
    int i = blockIdx.x * 256 + threadIdx.x;     // 385536 total
    if (i < 147456) da[i] = f2bf(a[i]);
    else if (i < 294912) db[i - 147456] = f2bf(b[i - 147456]);
    else if (i < 311808) dc[i - 294912] = f2bf(c[i - 294912]);
    else if (i < 385536) dd[i - 311808] = f2bf(d[i - 311808]);
}

// ---------------- depthwise causal conv1d + silu (dual out) -----------------
__global__ __launch_bounds__(256) void conv1d_silu(const float* __restrict__ xz,
                                                   const float* __restrict__ cw,
                                                   const float* __restrict__ cb,
                                                   float* __restrict__ u32,
                                                   unsigned short* __restrict__ u16)
{
    int idx = blockIdx.x * 256 + threadIdx.x;   // 8192*384
    int d = idx % 384;
    int row = idx / 384;
    int l = row & 1023;
    float acc = cb[d];
    #pragma unroll
    for (int j = 0; j < 4; ++j) {
        int ll = l - 3 + j;
        if (ll >= 0) acc += xz[(size_t)(row - 3 + j) * 768 + d] * cw[d * 4 + j];
    }
    float s = acc / (1.f + __expf(-acc));
    u32[idx] = s;
    u16[idx] = f2bf(s);
}

// ---------------- dt_proj + softplus ---------------------------------------
__global__ __launch_bounds__(256) void dtproj_softplus(const float* __restrict__ dbc,
                                                       const float* __restrict__ dtw,
                                                       const float* __restrict__ dtb,
                                                       float* __restrict__ delta)
{
    int idx = blockIdx.x * 256 + threadIdx.x;   // 8192*384
    int n = idx % 384, m = idx / 384;
    const float* row = dbc + (size_t)m * 44;
    const float* wr  = dtw + n * 12;
    float acc = dtb[n];
    #pragma unroll
    for (int j = 0; j < 12; ++j) acc = fmaf(row[j], wr[j], acc);
    delta[idx] = (acc > 20.f) ? acc : log1pf(__expf(acc));
}

// ---------------- selective scan, 3-pass: 32 chunks of 32 -------------------
// Block 256 = 64 d x 4 n4. Grid (32 c, 6 dg, 8 b). blk = (b*6+dg)*32+c.
__global__ __launch_bounds__(256) void ssm_pass1(const float* __restrict__ delta,
                                                 const float* __restrict__ dbc,
                                                 const float* __restrict__ u,
                                                 const float* __restrict__ A_log,
                                                 float* __restrict__ Pc,
                                                 float* __restrict__ Hc)
{
    const int tid = threadIdx.x;
    const int n4 = tid & 3, dloc = tid >> 2;
    const int c = blockIdx.x, dg = blockIdx.y, b = blockIdx.z;
    const int d = dg * 64 + dloc;
    const int blk = (b * 6 + dg) * 32 + c;
    f32x4 A4 = *(const f32x4*)(A_log + d * 16 + n4 * 4);
    float Aa[4];
    #pragma unroll
    for (int j = 0; j < 4; ++j) Aa[j] = -__expf(A4[j]);
    const float* dp = delta + (size_t)(b * 1024) * 384 + d;
    const float* up = u     + (size_t)(b * 1024) * 384 + d;
    const float* bp = dbc   + (size_t)(b * 1024) * 44;
    float P[4] = {1.f, 1.f, 1.f, 1.f}, H[4] = {0.f, 0.f, 0.f, 0.f};
    const int l0 = c * 32;
    for (int l = l0; l < l0 + 32; ++l) {
        float dlv = dp[(size_t)l * 384];
        float ulv = up[(size_t)l * 384];
        f32x4 B4 = *(const f32x4*)(bp + (size_t)l * 44 + 12 + n4 * 4);
        float du = dlv * ulv;
        #pragma unroll
        for (int j = 0; j < 4; ++j) {
            float a = __expf(dlv * Aa[j]);
            P[j] *= a;
            H[j] = fmaf(a, H[j], du * B4[j]);
        }
    }
    size_t o = ((size_t)blk * 256 + tid) * 4;
    *(f32x4*)(Pc + o) = (f32x4){P[0], P[1], P[2], P[3]};
    *(f32x4*)(Hc + o) = (f32x4){H[0], H[1], H[2], H[3]};
}

__global__ __launch_bounds__(256) void ssm_pass2(const float* __restrict__ Pc,
                                                 const float* __restrict__ Hc,
                                                 float* __restrict__ h0c)
{
    int t = blockIdx.x * 256 + threadIdx.x;    // 48*1024 = 49152
    int grp = t >> 10, dn = t & 1023;
    float h = 0.f;
    #pragma unroll
    for (int c = 0; c < 32; ++c) {
        size_t idx = ((size_t)(grp * 32 + c)) * 1024 + dn;
        h0c[idx] = h;
        h = fmaf(Pc[idx], h, Hc[idx]);
    }
}

__global__ __launch_bounds__(256) void ssm_pass3(const float* __restrict__ delta,
                                                 const float* __restrict__ dbc,
                                                 const float* __restrict__ u,
                                                 const float* __restrict__ xz,
                                                 const float* __restrict__ A_log,
                                                 const float* __restrict__ Dp,
                                                 const float* __restrict__ h0c,
                                                 unsigned short* __restrict__ y16)
{
    const int tid = threadIdx.x;
    const int n4 = tid & 3, dloc = tid >> 2;
    const int c = blockIdx.x, dg = blockIdx.y, b = blockIdx.z;
    const int d = dg * 64 + dloc;
    const int blk = (b * 6 + dg) * 32 + c;
    f32x4 A4 = *(const f32x4*)(A_log + d * 16 + n4 * 4);
    float Aa[4];
    #pragma unroll
    for (int j = 0; j < 4; ++j) Aa[j] = -__expf(A4[j]);
    float Dv = Dp[d];
    const float* dp = delta + (size_t)(b * 1024) * 384 + d;
    const float* up = u     + (size_t)(b * 1024) * 384 + d;
    const float* bp = dbc   + (size_t)(b * 1024) * 44;
    const float* zp = xz    + (size_t)(b * 1024) * 768 + 384 + d;
    unsigned short* yp = y16 + (size_t)(b * 1024) * 384 + d;
    f32x4 h4 = *(const f32x4*)(h0c + ((size_t)blk * 256 + tid) * 4);
    float H[4] = {h4[0], h4[1], h4[2], h4[3]};
    const int l0 = c * 32;
    for (int l = l0; l < l0 + 32; ++l) {
        float dlv = dp[(size_t)l * 384];
        float ulv = up[(size_t)l * 384];
        f32x4 B4 = *(const f32x4*)(bp + (size_t)l * 44 + 12 + n4 * 4);
        f32x4 C4 = *(const f32x4*)(bp + (size_t)l * 44 + 28 + n4 * 4);
        float du = dlv * ulv;
        float part = 0.f;
        #pragma unroll
        for (int j = 0; j < 4; ++j) {
            float a = __expf(dlv * Aa[j]);
            H[j] = fmaf(a, H[j], du * B4[j]);
            part = fmaf(H[j], C4[j], part);
        }
        part += __shfl_xor(part, 1, 4);
        part += __shfl_xor(part, 2, 4);
        if (n4 == 0) {
            float z = zp[(size_t)l * 768];
            float sz = z / (1.f + __expf(-z));
            yp[(size_t)l * 384] = f2bf((part + ulv * Dv) * sz);
        }
    }
}

// deconv_w (192,64,16,16) fp32 -> W2b[n'][c] bf16, n' = (p*16+q)*64 + k
__global__ __launch_bounds__(256) void transpose_w_bf16(const float* __restrict__ src,
                                                        unsigned short* __restrict__ dst)
{
    int idx = blockIdx.x * 256 + threadIdx.x;  // 16384*192
    int c = idx % 192;
    int np = idx / 192;
    int k = np & 63;
    int pq = np >> 6;
    dst[idx] = f2bf(src[(size_t)c * 16384 + k * 256 + pq]);
}

// dec_conv_w (3,64,3,3) -> dwr[((co*3+dy)*3+dx)*64 + k]
__global__ void rearrange_dcw(const float* __restrict__ src, float* __restrict__ dst)
{
    int i = blockIdx.x * 256 + threadIdx.x;
    if (i >= 1728) return;
    int k = i & 63;
    int r = i >> 6;
    int co = r / 9;
    int dydx = r % 9;
    int dy = dydx / 3, dx = dydx % 3;
    dst[i] = src[((co * 64 + k) * 3 + dy) * 3 + dx];
}

// ---------------- LDS-staged 3x3 conv, k-split 2 phases, 2 batches ----------
// LDS 18x18 px x 32 ch (pad 40) = 25.9 KB -> 6 blocks/CU.
__global__ __launch_bounds__(256) void decconv_sigmoid3(
    const unsigned short* __restrict__ Db, const float* __restrict__ dwr,
    const float* __restrict__ dcb, float* __restrict__ out, int pair)
{
    __shared__ unsigned short ds[18 * 18 * 40];
    const int t = threadIdx.x;
    const int pidx = blockIdx.x;            // h*32 + w
    const int bb = blockIdx.y;
    const int b = pair * 2 + bb;
    const unsigned short* Dbb = Db + (size_t)bb * 16777216;
    const int ph = pidx >> 5, pw = pidx & 31;
    const int px = t & 15, py = t >> 4;
    float a0 = dcb[0], a1 = dcb[1], a2 = dcb[2];
    const uint4 z4 = {0, 0, 0, 0};

    #pragma unroll
    for (int kh = 0; kh < 2; ++kh) {
        const int ko = kh * 32;
        // center 16x16 x 32ch
        const unsigned short* base = Dbb + ((size_t)pidx << 14) + ko;
        #pragma unroll
        for (int s = 0; s < 4; ++s) {
            int f = s * 256 + t;
            int k8 = f & 3, pq = f >> 2;
            *(uint4*)&ds[(((pq >> 4) + 1) * 18 + (pq & 15) + 1) * 40 + k8 * 8] =
                *(const uint4*)(base + pq * 64 + k8 * 8);
        }
        // edges: 4 sides x 16 px x 4 k8
        {
            int k8 = t & 3, e = (t >> 2) & 15, side = t >> 6;
            uint4 v = z4;
            int dsrow, dscol;
            if (side == 0) {
                if (ph > 0) v = *(const uint4*)(Dbb + ((size_t)(pidx - 32) << 14) + (240 + e) * 64 + ko + k8 * 8);
                dsrow = 0; dscol = e + 1;
            } else if (side == 1) {
                if (ph < 31) v = *(const uint4*)(Dbb + ((size_t)(pidx + 32) << 14) + e * 64 + ko + k8 * 8);
                dsrow = 17; dscol = e + 1;
            } else if (side == 2) {
                if (pw > 0) v = *(const uint4*)(Dbb + ((size_t)(pidx - 1) << 14) + (e * 16 + 15) * 64 + ko + k8 * 8);
                dsrow = e + 1; dscol = 0;
            } else {
                if (pw < 31) v = *(const uint4*)(Dbb + ((size_t)(pidx + 1) << 14) + (e * 16) * 64 + ko + k8 * 8);
                dsrow = e + 1; dscol = 17;
            }
            *(uint4*)&ds[(dsrow * 18 + dscol) * 40 + k8 * 8] = v;
        }
        if (t < 16) {                   // corners
            int c = t >> 2, k8 = t & 3;
            int dh = (c >> 1) * 2 - 1, dw = (c & 1) * 2 - 1;
            int nh = ph + dh, nw = pw + dw;
            uint4 v = z4;
            if (nh >= 0 && nh < 32 && nw >= 0 && nw < 32) {
                int sp = dh < 0 ? 15 : 0, sq = dw < 0 ? 15 : 0;
                v = *(const uint4*)(Dbb + ((size_t)(nh * 32 + nw) << 14) + (sp * 16 + sq) * 64 + ko + k8 * 8);
            }
            *(uint4*)&ds[((dh < 0 ? 0 : 17) * 18 + (dw < 0 ? 0 : 17)) * 40 + k8 * 8] = v;
        }
        __syncthreads();

        #pragma unroll
        for (int dy = 0; dy < 3; ++dy)
            #pragma unroll
            for (int dx = 0; dx < 3; ++dx) {
                const unsigned short* cell = &ds[((py + dy) * 18 + (px + dx)) * 40];
                const float* w0 = dwr + (0 * 9 + dy * 3 + dx) * 64 + ko;
                const float* w1 = dwr + (1 * 9 + dy * 3 + dx) * 64 + ko;
                const float* w2 = dwr + (2 * 9 + dy * 3 + dx) * 64 + ko;
                #pragma unroll
                for (int k8 = 0; k8 < 4; ++k8) {
                    uint4 v = *(const uint4*)(cell + k8 * 8);
                    unsigned int uu[4] = {v.x, v.y, v.z, v.w};
                    #pragma unroll
                    for (int m2 = 0; m2 < 4; ++m2) {
                        float flo = __uint_as_float(uu[m2] << 16);
                        float fhi = __uint_as_float(uu[m2] & 0xffff0000u);
                        int k = k8 * 8 + m2 * 2;
                        a0 += flo * w0[k] + fhi * w0[k + 1];
                        a1 += flo * w1[k] + fhi * w1[k + 1];
                        a2 += flo * w2[k] + fhi * w2[k + 1];
                    }
                }
            }
        __syncthreads();
    }

    int Y = ph * 16 + py, X = pw * 16 + px;
    size_t o = (size_t)(b * 3) * 262144 + (size_t)Y * 512 + X;
    out[o]          = 1.f / (1.f + __expf(-a0));
    out[o + 262144] = 1.f / (1.f + __expf(-a1));
    out[o + 524288] = 1.f / (1.f + __expf(-a2));
}

// ---------------------------------------------------------------------------
// Workspace (float units). Used: 19,331,008 floats = 77.3 MB.
// Aliasing: delta over dead P16; dbc over dead seq16; y16 over dead u16;
// Db (2-batch, [0,16777216)) + seqo_b + W2b over everything dead post-scan.
// ---------------------------------------------------------------------------
#define WS_P16      0            // bf16 8192x768 (3145728 f), dead after patch gemm
#define WS_DELTA    0            // f32 8192x384
#define WS_SEQ16    3145728      // bf16 8192x192 (786432 f), dead after in_proj
#define WS_DBC      3145728      // f32 8192x44 (360448 f)
#define WS_XZ       3932160      // f32 8192x768 -> ends 10223616
#define WS_U32      10223616     // f32 8192x384 -> ends 13369344
#define WS_U16      13369344     // bf16 (786432 f), dead after x_proj
#define WS_Y16      13369344     // bf16, aliases u16
#define WS_PC       14155776     // 1572864 -> 15728640
#define WS_HC       15728640     // 1572864 -> 17301504
#define WS_H0C      17301504     // 1572864 -> 18874368
#define WS_DB       0            // decoder: 2 x 8388608 = [0, 16777216)
#define WS_SEQOB    16777216     // bf16 (786432 f) -> 17563648 (post-scan)
#define WS_W2       17563648     // bf16 16384x192 (1572864 f) -> 19136512
#define WS_WP16     19136512     // 73728
#define WS_WI16     19210240     // 73728
#define WS_WX16     19283968     // 8448
#define WS_WO16     19292416     // 36864
#define WS_DWR      19329280     // 1728 -> 19331008

extern "C" void kernel_launch(void* const* d_in, const int* in_sizes, int n_in,
                              void* d_out, int out_size, void* d_ws, size_t ws_size,
                              hipStream_t stream)
{
    const float* x         = (const float*)d_in[0];
    const float* patch_w   = (const float*)d_in[1];
    const float* patch_b   = (const float*)d_in[2];
    const float* in_proj_w = (const float*)d_in[3];
    const float* conv1d_w  = (const float*)d_in[4];
    const float* conv1d_b  = (const float*)d_in[5];
    const float* x_proj_w  = (const float*)d_in[6];
    const float* dt_proj_w = (const float*)d_in[7];
    const float* dt_proj_b = (const float*)d_in[8];
    const float* A_log     = (const float*)d_in[9];
    const float* Dp        = (const float*)d_in[10];
    const float* out_proj_w= (const float*)d_in[11];
    const float* deconv_w  = (const float*)d_in[12];
    const float* deconv_b  = (const float*)d_in[13];
    const float* dec_conv_w= (const float*)d_in[14];
    const float* dec_conv_b= (const float*)d_in[15];
    float* out = (float*)d_out;
    float* ws  = (float*)d_ws;

    unsigned short* P16   = (unsigned short*)(ws + WS_P16);
    float*          delta = ws + WS_DELTA;
    unsigned short* seq16 = (unsigned short*)(ws + WS_SEQ16);
    float*          dbc   = ws + WS_DBC;
    float*          xz    = ws + WS_XZ;
    float*          u32   = ws + WS_U32;
    unsigned short* u16   = (unsigned short*)(ws + WS_U16);
    unsigned short* y16   = (unsigned short*)(ws + WS_Y16);
    float*          Pc    = ws + WS_PC;
    float*          Hc    = ws + WS_HC;
    float*          h0c   = ws + WS_H0C;
    unsigned short* Db16  = (unsigned short*)(ws + WS_DB);
    unsigned short* seqo_b= (unsigned short*)(ws + WS_SEQOB);
    unsigned short* W2b   = (unsigned short*)(ws + WS_W2);
    unsigned short* wp16  = (unsigned short*)(ws + WS_WP16);
    unsigned short* wi16  = (unsigned short*)(ws + WS_WI16);
    unsigned short* wx16  = (unsigned short*)(ws + WS_WX16);
    unsigned short* wo16  = (unsigned short*)(ws + WS_WO16);
    float*          dwr   = ws + WS_DWR;

    // 1. im2col -> bf16 + weight converts (one fused launch)
    im2col_bf16<<<24576, 256, 0, stream>>>(x, P16);
    f2b_all<<<1506, 256, 0, stream>>>(patch_w, wp16, in_proj_w, wi16,
                                      x_proj_w, wx16, out_proj_w, wo16);
    // 2. patch embedding -> seq16 bf16
    gemm_mfma_flex<<<dim3(2, 64), 256, 0, stream>>>(P16, wp16, seq16, patch_b,
                                                    8192, 192, 768, 1);
    // 3. in_proj -> xz fp32
    gemm_mfma_flex<<<dim3(6, 64), 256, 0, stream>>>(seq16, wi16, xz, nullptr,
                                                    8192, 768, 192, 0);
    // 4. conv1d + silu -> u32 + u16
    conv1d_silu<<<12288, 256, 0, stream>>>(xz, conv1d_w, conv1d_b, u32, u16);
    // 5. x_proj -> dbc fp32
    gemm_mfma_flex<<<dim3(1, 64), 256, 0, stream>>>(u16, wx16, dbc, nullptr,
                                                    8192, 44, 384, 0);
    // 6. dt_proj + softplus -> delta
    dtproj_softplus<<<12288, 256, 0, stream>>>(dbc, dt_proj_w, dt_proj_b, delta);
    // 7. selective scan (3-pass, 32 chunks of 32)
    ssm_pass1<<<dim3(32, 6, 8), 256, 0, stream>>>(delta, dbc, u32, A_log, Pc, Hc);
    ssm_pass2<<<192, 256, 0, stream>>>(Pc, Hc, h0c);
    ssm_pass3<<<dim3(32, 6, 8), 256, 0, stream>>>(delta, dbc, u32, xz, A_log, Dp, h0c, y16);
    // 8. out_proj -> seqo_b bf16
    gemm_mfma_flex<<<dim3(2, 64), 256, 0, stream>>>(y16, wo16, seqo_b, nullptr,
                                                    8192, 192, 384, 1);
    // 9. decoder weight prep
    transpose_w_bf16<<<12288, 256, 0, stream>>>(deconv_w, W2b);
    rearrange_dcw<<<7, 256, 0, stream>>>(dec_conv_w, dwr);
    // 10. decoder: 4 pairs x (2-batch MFMA GEMM -> 2-batch conv+sigmoid)
    for (int pair = 0; pair < 4; ++pair) {
        gemm_mfma_relu_bf16<<<dim3(128, 8, 2), 256, 0, stream>>>(
            seqo_b, W2b, Db16, deconv_b, pair);
        decconv_sigmoid3<<<dim3(1024, 2), 256, 0, stream>>>(Db16, dwr, dec_conv_b, out, pair);
    }
}

// Round 6
// 551.428 us; speedup vs baseline: 1.7760x; 1.7760x over previous
//
#include <hip/hip_runtime.h>
#include <math.h>

// ---------------------------------------------------------------------------
// VisionMambaDenoiser. Round 6: decoder 3x3 conv moved onto MFMA (scalar
// version was VALU-issue-bound; pad-40 k-split regressed with bank conflicts).
// Keeps round-5's coalesced-store deconv GEMM and 32-chunk scan.
// ---------------------------------------------------------------------------

typedef short bf16x8 __attribute__((ext_vector_type(8)));
typedef float f32x4 __attribute__((ext_vector_type(4)));

__device__ inline unsigned short f2bf(float f) {
    unsigned int u = __float_as_uint(f);
    unsigned int r = (u + 0x7fff + ((u >> 16) & 1)) >> 16;   // RNE
    return (unsigned short)r;
}

// ---------------- flexible bf16 MFMA GEMM: C = A @ W^T (+bias) --------------
__global__ __launch_bounds__(256) void gemm_mfma_flex(
    const unsigned short* __restrict__ A, const unsigned short* __restrict__ W,
    void* __restrict__ Cout, const float* __restrict__ bias,
    int M, int N, int K, int out_bf16)
{
    __shared__ unsigned short As[128][48];
    __shared__ unsigned short Bs[128][48];
    const int tid = threadIdx.x;
    const int wave = tid >> 6, lane = tid & 63;
    const int wm = (wave & 1) * 64, wn = (wave >> 1) * 64;
    const int m0 = blockIdx.y * 128, n0 = blockIdx.x * 128;
    const int quad = lane >> 4, lr = lane & 15;
    const uint4 z4 = {0, 0, 0, 0};

    f32x4 acc[4][4];
    #pragma unroll
    for (int i = 0; i < 4; ++i)
        #pragma unroll
        for (int j = 0; j < 4; ++j)
            acc[i][j] = (f32x4){0.f, 0.f, 0.f, 0.f};

    const int r = tid >> 2, kq = tid & 3;
    for (int k0 = 0; k0 < K; k0 += 32) {
        #pragma unroll
        for (int half = 0; half < 2; ++half) {
            int rr = r + half * 64;
            *(uint4*)(&As[rr][kq * 8]) =
                *(const uint4*)(A + (size_t)(m0 + rr) * K + k0 + kq * 8);
            uint4 bv = z4;
            if (n0 + rr < N)
                bv = *(const uint4*)(W + (size_t)(n0 + rr) * K + k0 + kq * 8);
            *(uint4*)(&Bs[rr][kq * 8]) = bv;
        }
        __syncthreads();
        bf16x8 af[4], bfr[4];
        #pragma unroll
        for (int i = 0; i < 4; ++i) af[i] = *(const bf16x8*)(&As[wm + i * 16 + lr][quad * 8]);
        #pragma unroll
        for (int j = 0; j < 4; ++j) bfr[j] = *(const bf16x8*)(&Bs[wn + j * 16 + lr][quad * 8]);
        #pragma unroll
        for (int i = 0; i < 4; ++i)
            #pragma unroll
            for (int j = 0; j < 4; ++j)
                acc[i][j] = __builtin_amdgcn_mfma_f32_16x16x32_bf16(af[i], bfr[j], acc[i][j], 0, 0, 0);
        __syncthreads();
    }

    #pragma unroll
    for (int i = 0; i < 4; ++i) {
        int gm = m0 + wm + i * 16 + quad * 4;
        #pragma unroll
        for (int j = 0; j < 4; ++j) {
            int gn = n0 + wn + j * 16 + lr;
            if (gn >= N) continue;
            float bv = bias ? bias[gn] : 0.f;
            #pragma unroll
            for (int rr = 0; rr < 4; ++rr) {
                float v = acc[i][j][rr] + bv;
                if (out_bf16) ((unsigned short*)Cout)[(size_t)(gm + rr) * N + gn] = f2bf(v);
                else          ((float*)Cout)[(size_t)(gm + rr) * N + gn] = v;
            }
        }
    }
}

// ---------------- decoder MFMA GEMM (2 batches): Db=bf16(relu(A@W^T+b)) -----
// Coalesced epilogue: C-tile staged in LDS, dwordx4 stores. (R5: ~10 us/batch)
__global__ __launch_bounds__(256) void gemm_mfma_relu_bf16(
    const unsigned short* __restrict__ A0, const unsigned short* __restrict__ W,
    unsigned short* __restrict__ C0, const float* __restrict__ bias, int pair)
{
    __shared__ unsigned short smem[12288];       // As | Bs, reused as Ct
    unsigned short* As = smem;                   // [128][48]
    unsigned short* Bs = smem + 6144;            // [128][48]
    const int N = 16384, K = 192;
    const int tid = threadIdx.x;
    const int wave = tid >> 6, lane = tid & 63;
    const int wm = (wave & 1) * 64, wn = (wave >> 1) * 64;
    const int m0 = blockIdx.y * 128, n0 = blockIdx.x * 128;
    const int z = blockIdx.z;
    const unsigned short* A = A0 + (size_t)(pair * 2 + z) * 1024 * 192;
    unsigned short* C = C0 + (size_t)z * 16777216;
    const int quad = lane >> 4, lr = lane & 15;

    f32x4 acc[4][4];
    #pragma unroll
    for (int i = 0; i < 4; ++i)
        #pragma unroll
        for (int j = 0; j < 4; ++j)
            acc[i][j] = (f32x4){0.f, 0.f, 0.f, 0.f};

    const int r = tid >> 2, kq = tid & 3;
    for (int k0 = 0; k0 < K; k0 += 32) {
        #pragma unroll
        for (int half = 0; half < 2; ++half) {
            int rr = r + half * 64;
            *(uint4*)(&As[rr * 48 + kq * 8]) =
                *(const uint4*)(A + (size_t)(m0 + rr) * K + k0 + kq * 8);
            *(uint4*)(&Bs[rr * 48 + kq * 8]) =
                *(const uint4*)(W + (size_t)(n0 + rr) * K + k0 + kq * 8);
        }
        __syncthreads();
        bf16x8 af[4], bfr[4];
        #pragma unroll
        for (int i = 0; i < 4; ++i) af[i] = *(const bf16x8*)(&As[(wm + i * 16 + lr) * 48 + quad * 8]);
        #pragma unroll
        for (int j = 0; j < 4; ++j) bfr[j] = *(const bf16x8*)(&Bs[(wn + j * 16 + lr) * 48 + quad * 8]);
        #pragma unroll
        for (int i = 0; i < 4; ++i)
            #pragma unroll
            for (int j = 0; j < 4; ++j)
                acc[i][j] = __builtin_amdgcn_mfma_f32_16x16x32_bf16(af[i], bfr[j], acc[i][j], 0, 0, 0);
        __syncthreads();
    }

    unsigned short* Ct = smem;                   // 64*136 = 8704 <= 12288
    #pragma unroll
    for (int h = 0; h < 2; ++h) {
        if ((wave & 1) == h) {
            #pragma unroll
            for (int i = 0; i < 4; ++i) {
                int lrow = i * 16 + quad * 4;
                #pragma unroll
                for (int j = 0; j < 4; ++j) {
                    int lcol = wn + j * 16 + lr;
                    float bv = bias[(n0 + lcol) & 63];
                    #pragma unroll
                    for (int rr = 0; rr < 4; ++rr) {
                        float v = fmaxf(acc[i][j][rr] + bv, 0.f);
                        Ct[(lrow + rr) * 136 + lcol] = f2bf(v);
                    }
                }
            }
        }
        __syncthreads();
        #pragma unroll
        for (int p = 0; p < 4; ++p) {
            int idx = p * 256 + tid;             // 0..1023
            int row = idx >> 4, cg = idx & 15;
            *(uint4*)(C + (size_t)(m0 + h * 64 + row) * N + n0 + cg * 8) =
                *(const uint4*)(&Ct[row * 136 + cg * 8]);
        }
        __syncthreads();
    }
}

// ---------------- im2col of 16x16 patches -> bf16 ---------------------------
__global__ __launch_bounds__(256) void im2col_bf16(const float* __restrict__ x,
                                                   unsigned short* __restrict__ P)
{
    int idx = blockIdx.x * 256 + threadIdx.x;   // 8192*768
    int col = idx % 768;
    int row = idx / 768;
    int b = row >> 10;
    int l = row & 1023;
    int h = l >> 5, w = l & 31;
    int c = col >> 8;
    int p = (col >> 4) & 15, q = col & 15;
    P[idx] = f2bf(x[((size_t)(b * 3 + c) * 512 + (h * 16 + p)) * 512 + (w * 16 + q)]);
}

// ---------------- fused fp32 -> bf16 weight converts ------------------------
__global__ __launch_bounds__(256) void f2b_all(
    const float* __restrict__ a, unsigned short* __restrict__ da,
    const float* __restrict__ b, unsigned short* __restrict__ db,
    const float* __restrict__ c, unsigned short* __restrict__ dc,
    const float* __restrict__ d, unsigned short* __restrict__ dd)
{
    int i = blockIdx.x * 256 + threadIdx.x;     // 385536 total
    if (i < 147456) da[i] = f2bf(a[i]);
    else if (i < 294912) db[i - 147456] = f2bf(b[i - 147456]);
    else if (i < 311808) dc[i - 294912] = f2bf(c[i - 294912]);
    else if (i < 385536) dd[i - 311808] = f2bf(d[i - 311808]);
}

// ---------------- depthwise causal conv1d + silu (dual out) -----------------
__global__ __launch_bounds__(256) void conv1d_silu(const float* __restrict__ xz,
                                                   const float* __restrict__ cw,
                                                   const float* __restrict__ cb,
                                                   float* __restrict__ u32,
                                                   unsigned short* __restrict__ u16)
{
    int idx = blockIdx.x * 256 + threadIdx.x;   // 8192*384
    int d = idx % 384;
    int row = idx / 384;
    int l = row & 1023;
    float acc = cb[d];
    #pragma unroll
    for (int j = 0; j < 4; ++j) {
        int ll = l - 3 + j;
        if (ll >= 0) acc += xz[(size_t)(row - 3 + j) * 768 + d] * cw[d * 4 + j];
    }
    float s = acc / (1.f + __expf(-acc));
    u32[idx] = s;
    u16[idx] = f2bf(s);
}

// ---------------- dt_proj + softplus ---------------------------------------
__global__ __launch_bounds__(256) void dtproj_softplus(const float* __restrict__ dbc,
                                                       const float* __restrict__ dtw,
                                                       const float* __restrict__ dtb,
                                                       float* __restrict__ delta)
{
    int idx = blockIdx.x * 256 + threadIdx.x;   // 8192*384
    int n = idx % 384, m = idx / 384;
    const float* row = dbc + (size_t)m * 44;
    const float* wr  = dtw + n * 12;
    float acc = dtb[n];
    #pragma unroll
    for (int j = 0; j < 12; ++j) acc = fmaf(row[j], wr[j], acc);
    delta[idx] = (acc > 20.f) ? acc : log1pf(__expf(acc));
}

// ---------------- selective scan, 3-pass: 32 chunks of 32 -------------------
__global__ __launch_bounds__(256) void ssm_pass1(const float* __restrict__ delta,
                                                 const float* __restrict__ dbc,
                                                 const float* __restrict__ u,
                                                 const float* __restrict__ A_log,
                                                 float* __restrict__ Pc,
                                                 float* __restrict__ Hc)
{
    const int tid = threadIdx.x;
    const int n4 = tid & 3, dloc = tid >> 2;
    const int c = blockIdx.x, dg = blockIdx.y, b = blockIdx.z;
    const int d = dg * 64 + dloc;
    const int blk = (b * 6 + dg) * 32 + c;
    f32x4 A4 = *(const f32x4*)(A_log + d * 16 + n4 * 4);
    float Aa[4];
    #pragma unroll
    for (int j = 0; j < 4; ++j) Aa[j] = -__expf(A4[j]);
    const float* dp = delta + (size_t)(b * 1024) * 384 + d;
    const float* up = u     + (size_t)(b * 1024) * 384 + d;
    const float* bp = dbc   + (size_t)(b * 1024) * 44;
    float P[4] = {1.f, 1.f, 1.f, 1.f}, H[4] = {0.f, 0.f, 0.f, 0.f};
    const int l0 = c * 32;
    for (int l = l0; l < l0 + 32; ++l) {
        float dlv = dp[(size_t)l * 384];
        float ulv = up[(size_t)l * 384];
        f32x4 B4 = *(const f32x4*)(bp + (size_t)l * 44 + 12 + n4 * 4);
        float du = dlv * ulv;
        #pragma unroll
        for (int j = 0; j < 4; ++j) {
            float a = __expf(dlv * Aa[j]);
            P[j] *= a;
            H[j] = fmaf(a, H[j], du * B4[j]);
        }
    }
    size_t o = ((size_t)blk * 256 + tid) * 4;
    *(f32x4*)(Pc + o) = (f32x4){P[0], P[1], P[2], P[3]};
    *(f32x4*)(Hc + o) = (f32x4){H[0], H[1], H[2], H[3]};
}

__global__ __launch_bounds__(256) void ssm_pass2(const float* __restrict__ Pc,
                                                 const float* __restrict__ Hc,
                                                 float* __restrict__ h0c)
{
    int t = blockIdx.x * 256 + threadIdx.x;    // 48*1024 = 49152
    int grp = t >> 10, dn = t & 1023;
    float h = 0.f;
    #pragma unroll
    for (int c = 0; c < 32; ++c) {
        size_t idx = ((size_t)(grp * 32 + c)) * 1024 + dn;
        h0c[idx] = h;
        h = fmaf(Pc[idx], h, Hc[idx]);
    }
}

__global__ __launch_bounds__(256) void ssm_pass3(const float* __restrict__ delta,
                                                 const float* __restrict__ dbc,
                                                 const float* __restrict__ u,
                                                 const float* __restrict__ xz,
                                                 const float* __restrict__ A_log,
                                                 const float* __restrict__ Dp,
                                                 const float* __restrict__ h0c,
                                                 unsigned short* __restrict__ y16)
{
    const int tid = threadIdx.x;
    const int n4 = tid & 3, dloc = tid >> 2;
    const int c = blockIdx.x, dg = blockIdx.y, b = blockIdx.z;
    const int d = dg * 64 + dloc;
    const int blk = (b * 6 + dg) * 32 + c;
    f32x4 A4 = *(const f32x4*)(A_log + d * 16 + n4 * 4);
    float Aa[4];
    #pragma unroll
    for (int j = 0; j < 4; ++j) Aa[j] = -__expf(A4[j]);
    float Dv = Dp[d];
    const float* dp = delta + (size_t)(b * 1024) * 384 + d;
    const float* up = u     + (size_t)(b * 1024) * 384 + d;
    const float* bp = dbc   + (size_t)(b * 1024) * 44;
    const float* zp = xz    + (size_t)(b * 1024) * 768 + 384 + d;
    unsigned short* yp = y16 + (size_t)(b * 1024) * 384 + d;
    f32x4 h4 = *(const f32x4*)(h0c + ((size_t)blk * 256 + tid) * 4);
    float H[4] = {h4[0], h4[1], h4[2], h4[3]};
    const int l0 = c * 32;
    for (int l = l0; l < l0 + 32; ++l) {
        float dlv = dp[(size_t)l * 384];
        float ulv = up[(size_t)l * 384];
        f32x4 B4 = *(const f32x4*)(bp + (size_t)l * 44 + 12 + n4 * 4);
        f32x4 C4 = *(const f32x4*)(bp + (size_t)l * 44 + 28 + n4 * 4);
        float du = dlv * ulv;
        float part = 0.f;
        #pragma unroll
        for (int j = 0; j < 4; ++j) {
            float a = __expf(dlv * Aa[j]);
            H[j] = fmaf(a, H[j], du * B4[j]);
            part = fmaf(H[j], C4[j], part);
        }
        part += __shfl_xor(part, 1, 4);
        part += __shfl_xor(part, 2, 4);
        if (n4 == 0) {
            float z = zp[(size_t)l * 768];
            float sz = z / (1.f + __expf(-z));
            yp[(size_t)l * 384] = f2bf((part + ulv * Dv) * sz);
        }
    }
}

// deconv_w (192,64,16,16) fp32 -> W2b[n'][c] bf16, n' = (p*16+q)*64 + k
__global__ __launch_bounds__(256) void transpose_w_bf16(const float* __restrict__ src,
                                                        unsigned short* __restrict__ dst)
{
    int idx = blockIdx.x * 256 + threadIdx.x;  // 16384*192
    int c = idx % 192;
    int np = idx / 192;
    int k = np & 63;
    int pq = np >> 6;
    dst[idx] = f2bf(src[(size_t)c * 16384 + k * 256 + pq]);
}

// dec_conv_w (3,64,3,3) -> MFMA A-operand table wconv[tap=dy*3+dx][m=co(16)][ch(64)]
// rows m=3..15 zero-padded.
__global__ void prep_wconv(const float* __restrict__ w, unsigned short* __restrict__ wc)
{
    int i = blockIdx.x * 256 + threadIdx.x;    // 9*16*64 = 9216
    if (i >= 9216) return;
    int ch = i & 63;
    int m = (i >> 6) & 15;
    int tap = i >> 10;
    int dy = tap / 3, dx = tap % 3;
    float v = (m < 3) ? w[((m * 64 + ch) * 3 + dy) * 3 + dx] : 0.f;
    wc[i] = f2bf(v);
}

// ---------------- MFMA 3x3 conv (64->3) + bias + sigmoid, 2 batches ---------
// One block per 16x16 patch. LDS halo tile 18x18 px x 64ch, pad 72 (measured
// conflict-free). Per tap: out[co][px] += wconv_tap[co][ch] @ act[ch][px] as
// two 16x16x32 bf16 MFMAs; LDS tile read IS the B-operand layout.
__global__ __launch_bounds__(256) void decconv_mfma(
    const unsigned short* __restrict__ Db, const unsigned short* __restrict__ wconv,
    const float* __restrict__ dcb, float* __restrict__ out, int pair)
{
    __shared__ unsigned short ds[18 * 18 * 72];
    const int t = threadIdx.x;
    const int pidx = blockIdx.x;            // h*32 + w
    const int bb = blockIdx.y;
    const int b = pair * 2 + bb;
    const unsigned short* Dbb = Db + (size_t)bb * 16777216;
    const int ph = pidx >> 5, pw = pidx & 31;
    const uint4 z4 = {0, 0, 0, 0};

    // center 16x16x64 (32 KB contiguous)
    const unsigned short* base = Dbb + ((size_t)pidx << 14);
    #pragma unroll
    for (int s = 0; s < 8; ++s) {
        int f = s * 256 + t;
        int k8 = f & 7, pq = f >> 3;
        *(uint4*)&ds[(((pq >> 4) + 1) * 18 + (pq & 15) + 1) * 72 + k8 * 8] =
            *(const uint4*)(base + pq * 64 + k8 * 8);
    }
    // halo edges
    {
        int k8 = t & 7, e = (t >> 3) & 15;
        if (t < 128) {        // top
            uint4 v = z4;
            if (ph > 0) v = *(const uint4*)(Dbb + ((size_t)(pidx - 32) << 14) + (240 + e) * 64 + k8 * 8);
            *(uint4*)&ds[(0 * 18 + e + 1) * 72 + k8 * 8] = v;
        } else {              // bottom
            uint4 v = z4;
            if (ph < 31) v = *(const uint4*)(Dbb + ((size_t)(pidx + 32) << 14) + e * 64 + k8 * 8);
            *(uint4*)&ds[(17 * 18 + e + 1) * 72 + k8 * 8] = v;
        }
        if (t < 128) {        // left
            uint4 v = z4;
            if (pw > 0) v = *(const uint4*)(Dbb + ((size_t)(pidx - 1) << 14) + (e * 16 + 15) * 64 + k8 * 8);
            *(uint4*)&ds[((e + 1) * 18 + 0) * 72 + k8 * 8] = v;
        } else {              // right
            uint4 v = z4;
            if (pw < 31) v = *(const uint4*)(Dbb + ((size_t)(pidx + 1) << 14) + (e * 16) * 64 + k8 * 8);
            *(uint4*)&ds[((e + 1) * 18 + 17) * 72 + k8 * 8] = v;
        }
        if (t < 32) {         // corners
            int c = t >> 3;
            int dh = (c >> 1) * 2 - 1, dw = (c & 1) * 2 - 1;
            int nh = ph + dh, nw = pw + dw;
            int sp = dh < 0 ? 15 : 0, sq = dw < 0 ? 15 : 0;
            uint4 v = z4;
            if (nh >= 0 && nh < 32 && nw >= 0 && nw < 32)
                v = *(const uint4*)(Dbb + ((size_t)(nh * 32 + nw) << 14) + (sp * 16 + sq) * 64 + k8 * 8);
            int dy = dh < 0 ? 0 : 17, dx = dw < 0 ? 0 : 17;
            *(uint4*)&ds[(dy * 18 + dx) * 72 + k8 * 8] = v;
        }
    }
    __syncthreads();

    const int wave = t >> 6, lane = t & 63;
    const int quad = lane >> 4, lr = lane & 15;
    // wave w computes output rows p = w*4 + i (i=0..3), column q = lr.
    f32x4 acc[4];
    #pragma unroll
    for (int i = 0; i < 4; ++i) acc[i] = (f32x4){0.f, 0.f, 0.f, 0.f};

    #pragma unroll
    for (int tap = 0; tap < 9; ++tap) {
        const int dy = tap / 3, dx = tap % 3;
        // A-frags: A[m=lr][k=quad*8+j] from the global table (L1-hot)
        bf16x8 a0 = *(const bf16x8*)(wconv + (tap * 16 + lr) * 64 + quad * 8);
        bf16x8 a1 = *(const bf16x8*)(wconv + (tap * 16 + lr) * 64 + 32 + quad * 8);
        #pragma unroll
        for (int i = 0; i < 4; ++i) {
            int p = wave * 4 + i;
            const unsigned short* cell = &ds[((p + dy) * 18 + lr + dx) * 72];
            bf16x8 b0 = *(const bf16x8*)(cell + quad * 8);        // B[k=quad*8+j][n=lr]
            bf16x8 b1 = *(const bf16x8*)(cell + 32 + quad * 8);
            acc[i] = __builtin_amdgcn_mfma_f32_16x16x32_bf16(a0, b0, acc[i], 0, 0, 0);
            acc[i] = __builtin_amdgcn_mfma_f32_16x16x32_bf16(a1, b1, acc[i], 0, 0, 0);
        }
    }

    // D layout: col=lane&15, row=quad*4+reg. Rows 0..2 (quad 0) = channels.
    if (quad == 0) {
        float b0 = dcb[0], b1 = dcb[1], b2 = dcb[2];
        #pragma unroll
        for (int i = 0; i < 4; ++i) {
            int Y = ph * 16 + wave * 4 + i, X = pw * 16 + lr;
            size_t o = (size_t)(b * 3) * 262144 + (size_t)Y * 512 + X;
            out[o]          = 1.f / (1.f + __expf(-(acc[i][0] + b0)));
            out[o + 262144] = 1.f / (1.f + __expf(-(acc[i][1] + b1)));
            out[o + 524288] = 1.f / (1.f + __expf(-(acc[i][2] + b2)));
        }
    }
}

// ---------------------------------------------------------------------------
// Workspace (float units). Used: 19,333,888 floats = 77.3 MB.
// ---------------------------------------------------------------------------
#define WS_P16      0            // bf16 8192x768, dead after patch gemm
#define WS_DELTA    0            // f32 8192x384
#define WS_SEQ16    3145728      // bf16, dead after in_proj
#define WS_DBC      3145728      // f32 8192x44
#define WS_XZ       3932160      // f32 8192x768 -> 10223616
#define WS_U32      10223616     // f32 8192x384 -> 13369344
#define WS_U16      13369344     // bf16, dead after x_proj
#define WS_Y16      13369344     // bf16, aliases u16
#define WS_PC       14155776     // -> 15728640
#define WS_HC       15728640     // -> 17301504
#define WS_H0C      17301504     // -> 18874368
#define WS_DB       0            // decoder: 2 x 8388608 = [0, 16777216)
#define WS_SEQOB    16777216     // bf16 -> 17563648 (post-scan)
#define WS_W2       17563648     // bf16 16384x192 -> 19136512
#define WS_WP16     19136512     // 73728
#define WS_WI16     19210240     // 73728
#define WS_WX16     19283968     // 8448
#define WS_WO16     19292416     // 36864
#define WS_WCONV    19329280     // 4608 (bf16 9x16x64) -> 19333888

extern "C" void kernel_launch(void* const* d_in, const int* in_sizes, int n_in,
                              void* d_out, int out_size, void* d_ws, size_t ws_size,
                              hipStream_t stream)
{
    const float* x         = (const float*)d_in[0];
    const float* patch_w   = (const float*)d_in[1];
    const float* patch_b   = (const float*)d_in[2];
    const float* in_proj_w = (const float*)d_in[3];
    const float* conv1d_w  = (const float*)d_in[4];
    const float* conv1d_b  = (const float*)d_in[5];
    const float* x_proj_w  = (const float*)d_in[6];
    const float* dt_proj_w = (const float*)d_in[7];
    const float* dt_proj_b = (const float*)d_in[8];
    const float* A_log     = (const float*)d_in[9];
    const float* Dp        = (const float*)d_in[10];
    const float* out_proj_w= (const float*)d_in[11];
    const float* deconv_w  = (const float*)d_in[12];
    const float* deconv_b  = (const float*)d_in[13];
    const float* dec_conv_w= (const float*)d_in[14];
    const float* dec_conv_b= (const float*)d_in[15];
    float* out = (float*)d_out;
    float* ws  = (float*)d_ws;

    unsigned short* P16   = (unsigned short*)(ws + WS_P16);
    float*          delta = ws + WS_DELTA;
    unsigned short* seq16 = (unsigned short*)(ws + WS_SEQ16);
    float*          dbc   = ws + WS_DBC;
    float*          xz    = ws + WS_XZ;
    float*          u32   = ws + WS_U32;
    unsigned short* u16   = (unsigned short*)(ws + WS_U16);
    unsigned short* y16   = (unsigned short*)(ws + WS_Y16);
    float*          Pc    = ws + WS_PC;
    float*          Hc    = ws + WS_HC;
    float*          h0c   = ws + WS_H0C;
    unsigned short* Db16  = (unsigned short*)(ws + WS_DB);
    unsigned short* seqo_b= (unsigned short*)(ws + WS_SEQOB);
    unsigned short* W2b   = (unsigned short*)(ws + WS_W2);
    unsigned short* wp16  = (unsigned short*)(ws + WS_WP16);
    unsigned short* wi16  = (unsigned short*)(ws + WS_WI16);
    unsigned short* wx16  = (unsigned short*)(ws + WS_WX16);
    unsigned short* wo16  = (unsigned short*)(ws + WS_WO16);
    unsigned short* wconv = (unsigned short*)(ws + WS_WCONV);

    // 1. im2col -> bf16 + weight converts
    im2col_bf16<<<24576, 256, 0, stream>>>(x, P16);
    f2b_all<<<1506, 256, 0, stream>>>(patch_w, wp16, in_proj_w, wi16,
                                      x_proj_w, wx16, out_proj_w, wo16);
    // 2. patch embedding -> seq16 bf16
    gemm_mfma_flex<<<dim3(2, 64), 256, 0, stream>>>(P16, wp16, seq16, patch_b,
                                                    8192, 192, 768, 1);
    // 3. in_proj -> xz fp32
    gemm_mfma_flex<<<dim3(6, 64), 256, 0, stream>>>(seq16, wi16, xz, nullptr,
                                                    8192, 768, 192, 0);
    // 4. conv1d + silu -> u32 + u16
    conv1d_silu<<<12288, 256, 0, stream>>>(xz, conv1d_w, conv1d_b, u32, u16);
    // 5. x_proj -> dbc fp32
    gemm_mfma_flex<<<dim3(1, 64), 256, 0, stream>>>(u16, wx16, dbc, nullptr,
                                                    8192, 44, 384, 0);
    // 6. dt_proj + softplus -> delta
    dtproj_softplus<<<12288, 256, 0, stream>>>(dbc, dt_proj_w, dt_proj_b, delta);
    // 7. selective scan (3-pass, 32 chunks of 32)
    ssm_pass1<<<dim3(32, 6, 8), 256, 0, stream>>>(delta, dbc, u32, A_log, Pc, Hc);
    ssm_pass2<<<192, 256, 0, stream>>>(Pc, Hc, h0c);
    ssm_pass3<<<dim3(32, 6, 8), 256, 0, stream>>>(delta, dbc, u32, xz, A_log, Dp, h0c, y16);
    // 8. out_proj -> seqo_b bf16
    gemm_mfma_flex<<<dim3(2, 64), 256, 0, stream>>>(y16, wo16, seqo_b, nullptr,
                                                    8192, 192, 384, 1);
    // 9. decoder weight prep
    transpose_w_bf16<<<12288, 256, 0, stream>>>(deconv_w, W2b);
    prep_wconv<<<36, 256, 0, stream>>>(dec_conv_w, wconv);
    // 10. decoder: 4 pairs x (2-batch MFMA GEMM -> 2-batch MFMA conv+sigmoid)
    for (int pair = 0; pair < 4; ++pair) {
        gemm_mfma_relu_bf16<<<dim3(128, 8, 2), 256, 0, stream>>>(
            seqo_b, W2b, Db16, deconv_b, pair);
        decconv_mfma<<<dim3(1024, 2), 256, 0, stream>>>(Db16, wconv, dec_conv_b, out, pair);
    }
}

// Round 7
// 535.064 us; speedup vs baseline: 1.8303x; 1.0306x over previous
//
#include <hip/hip_runtime.h>
#include <math.h>

// ---------------------------------------------------------------------------
// VisionMambaDenoiser. Round 7: fused prep (im2col + all weight transforms),
// x_proj+dt_proj merged into one N=416 GEMM via precomposed Wdt@Wx12,
// bf16 xz, decoder in 4-batch groups (ws proven 256 MiB by harness fill).
// ---------------------------------------------------------------------------

typedef short bf16x8 __attribute__((ext_vector_type(8)));
typedef float f32x4 __attribute__((ext_vector_type(4)));

__device__ inline unsigned short f2bf(float f) {
    unsigned int u = __float_as_uint(f);
    unsigned int r = (u + 0x7fff + ((u >> 16) & 1)) >> 16;   // RNE
    return (unsigned short)r;
}
__device__ inline float bf2f(unsigned short s) {
    return __uint_as_float(((unsigned int)s) << 16);
}

// ---------------- flexible bf16 MFMA GEMM: C = A @ W^T (+bias) --------------
__global__ __launch_bounds__(256) void gemm_mfma_flex(
    const unsigned short* __restrict__ A, const unsigned short* __restrict__ W,
    void* __restrict__ Cout, const float* __restrict__ bias,
    int M, int N, int K, int out_bf16)
{
    __shared__ unsigned short As[128][48];
    __shared__ unsigned short Bs[128][48];
    const int tid = threadIdx.x;
    const int wave = tid >> 6, lane = tid & 63;
    const int wm = (wave & 1) * 64, wn = (wave >> 1) * 64;
    const int m0 = blockIdx.y * 128, n0 = blockIdx.x * 128;
    const int quad = lane >> 4, lr = lane & 15;
    const uint4 z4 = {0, 0, 0, 0};

    f32x4 acc[4][4];
    #pragma unroll
    for (int i = 0; i < 4; ++i)
        #pragma unroll
        for (int j = 0; j < 4; ++j)
            acc[i][j] = (f32x4){0.f, 0.f, 0.f, 0.f};

    const int r = tid >> 2, kq = tid & 3;
    for (int k0 = 0; k0 < K; k0 += 32) {
        #pragma unroll
        for (int half = 0; half < 2; ++half) {
            int rr = r + half * 64;
            *(uint4*)(&As[rr][kq * 8]) =
                *(const uint4*)(A + (size_t)(m0 + rr) * K + k0 + kq * 8);
            uint4 bv = z4;
            if (n0 + rr < N)
                bv = *(const uint4*)(W + (size_t)(n0 + rr) * K + k0 + kq * 8);
            *(uint4*)(&Bs[rr][kq * 8]) = bv;
        }
        __syncthreads();
        bf16x8 af[4], bfr[4];
        #pragma unroll
        for (int i = 0; i < 4; ++i) af[i] = *(const bf16x8*)(&As[wm + i * 16 + lr][quad * 8]);
        #pragma unroll
        for (int j = 0; j < 4; ++j) bfr[j] = *(const bf16x8*)(&Bs[wn + j * 16 + lr][quad * 8]);
        #pragma unroll
        for (int i = 0; i < 4; ++i)
            #pragma unroll
            for (int j = 0; j < 4; ++j)
                acc[i][j] = __builtin_amdgcn_mfma_f32_16x16x32_bf16(af[i], bfr[j], acc[i][j], 0, 0, 0);
        __syncthreads();
    }

    #pragma unroll
    for (int i = 0; i < 4; ++i) {
        int gm = m0 + wm + i * 16 + quad * 4;
        #pragma unroll
        for (int j = 0; j < 4; ++j) {
            int gn = n0 + wn + j * 16 + lr;
            if (gn >= N) continue;
            float bv = bias ? bias[gn] : 0.f;
            #pragma unroll
            for (int rr = 0; rr < 4; ++rr) {
                float v = acc[i][j][rr] + bv;
                if (out_bf16) ((unsigned short*)Cout)[(size_t)(gm + rr) * N + gn] = f2bf(v);
                else          ((float*)Cout)[(size_t)(gm + rr) * N + gn] = v;
            }
        }
    }
}

// ---------------- combined x_proj+dt_proj GEMM (N=416, K=384) --------------
// W rows 0..383 = Wdt@Wx12 (delta pre-act), rows 384..415 = x_proj rows 12..43.
// Epilogue: gn<384 -> softplus(v+dtb[gn]) into delta (ld 384);
//           gn>=384 -> v into bc (ld 32).
__global__ __launch_bounds__(256) void gemm_xd(
    const unsigned short* __restrict__ A, const unsigned short* __restrict__ W,
    float* __restrict__ delta, float* __restrict__ bc,
    const float* __restrict__ dtb)
{
    __shared__ unsigned short As[128][48];
    __shared__ unsigned short Bs[128][48];
    const int N = 416, K = 384;
    const int tid = threadIdx.x;
    const int wave = tid >> 6, lane = tid & 63;
    const int wm = (wave & 1) * 64, wn = (wave >> 1) * 64;
    const int m0 = blockIdx.y * 128, n0 = blockIdx.x * 128;
    const int quad = lane >> 4, lr = lane & 15;
    const uint4 z4 = {0, 0, 0, 0};

    f32x4 acc[4][4];
    #pragma unroll
    for (int i = 0; i < 4; ++i)
        #pragma unroll
        for (int j = 0; j < 4; ++j)
            acc[i][j] = (f32x4){0.f, 0.f, 0.f, 0.f};

    const int r = tid >> 2, kq = tid & 3;
    for (int k0 = 0; k0 < K; k0 += 32) {
        #pragma unroll
        for (int half = 0; half < 2; ++half) {
            int rr = r + half * 64;
            *(uint4*)(&As[rr][kq * 8]) =
                *(const uint4*)(A + (size_t)(m0 + rr) * K + k0 + kq * 8);
            uint4 bv = z4;
            if (n0 + rr < N)
                bv = *(const uint4*)(W + (size_t)(n0 + rr) * K + k0 + kq * 8);
            *(uint4*)(&Bs[rr][kq * 8]) = bv;
        }
        __syncthreads();
        bf16x8 af[4], bfr[4];
        #pragma unroll
        for (int i = 0; i < 4; ++i) af[i] = *(const bf16x8*)(&As[wm + i * 16 + lr][quad * 8]);
        #pragma unroll
        for (int j = 0; j < 4; ++j) bfr[j] = *(const bf16x8*)(&Bs[wn + j * 16 + lr][quad * 8]);
        #pragma unroll
        for (int i = 0; i < 4; ++i)
            #pragma unroll
            for (int j = 0; j < 4; ++j)
                acc[i][j] = __builtin_amdgcn_mfma_f32_16x16x32_bf16(af[i], bfr[j], acc[i][j], 0, 0, 0);
        __syncthreads();
    }

    #pragma unroll
    for (int i = 0; i < 4; ++i) {
        int gm = m0 + wm + i * 16 + quad * 4;
        #pragma unroll
        for (int j = 0; j < 4; ++j) {
            int gn = n0 + wn + j * 16 + lr;
            if (gn >= N) continue;
            #pragma unroll
            for (int rr = 0; rr < 4; ++rr) {
                float v = acc[i][j][rr];
                if (gn < 384) {
                    v += dtb[gn];
                    v = (v > 20.f) ? v : log1pf(__expf(v));
                    delta[(size_t)(gm + rr) * 384 + gn] = v;
                } else {
                    bc[(size_t)(gm + rr) * 32 + gn - 384] = v;
                }
            }
        }
    }
}

// ---------------- decoder MFMA GEMM (G batches): Db=bf16(relu(A@W^T+b)) -----
__global__ __launch_bounds__(256) void gemm_mfma_relu_bf16(
    const unsigned short* __restrict__ A0, const unsigned short* __restrict__ W,
    unsigned short* __restrict__ C0, const float* __restrict__ bias, int base_b)
{
    __shared__ unsigned short smem[12288];       // As | Bs, reused as Ct
    unsigned short* As = smem;
    unsigned short* Bs = smem + 6144;
    const int N = 16384, K = 192;
    const int tid = threadIdx.x;
    const int wave = tid >> 6, lane = tid & 63;
    const int wm = (wave & 1) * 64, wn = (wave >> 1) * 64;
    const int m0 = blockIdx.y * 128, n0 = blockIdx.x * 128;
    const int z = blockIdx.z;
    const unsigned short* A = A0 + (size_t)(base_b + z) * 1024 * 192;
    unsigned short* C = C0 + (size_t)z * 16777216;
    const int quad = lane >> 4, lr = lane & 15;

    f32x4 acc[4][4];
    #pragma unroll
    for (int i = 0; i < 4; ++i)
        #pragma unroll
        for (int j = 0; j < 4; ++j)
            acc[i][j] = (f32x4){0.f, 0.f, 0.f, 0.f};

    const int r = tid >> 2, kq = tid & 3;
    for (int k0 = 0; k0 < K; k0 += 32) {
        #pragma unroll
        for (int half = 0; half < 2; ++half) {
            int rr = r + half * 64;
            *(uint4*)(&As[rr * 48 + kq * 8]) =
                *(const uint4*)(A + (size_t)(m0 + rr) * K + k0 + kq * 8);
            *(uint4*)(&Bs[rr * 48 + kq * 8]) =
                *(const uint4*)(W + (size_t)(n0 + rr) * K + k0 + kq * 8);
        }
        __syncthreads();
        bf16x8 af[4], bfr[4];
        #pragma unroll
        for (int i = 0; i < 4; ++i) af[i] = *(const bf16x8*)(&As[(wm + i * 16 + lr) * 48 + quad * 8]);
        #pragma unroll
        for (int j = 0; j < 4; ++j) bfr[j] = *(const bf16x8*)(&Bs[(wn + j * 16 + lr) * 48 + quad * 8]);
        #pragma unroll
        for (int i = 0; i < 4; ++i)
            #pragma unroll
            for (int j = 0; j < 4; ++j)
                acc[i][j] = __builtin_amdgcn_mfma_f32_16x16x32_bf16(af[i], bfr[j], acc[i][j], 0, 0, 0);
        __syncthreads();
    }

    unsigned short* Ct = smem;                   // 64*136 = 8704 <= 12288
    #pragma unroll
    for (int h = 0; h < 2; ++h) {
        if ((wave & 1) == h) {
            #pragma unroll
            for (int i = 0; i < 4; ++i) {
                int lrow = i * 16 + quad * 4;
                #pragma unroll
                for (int j = 0; j < 4; ++j) {
                    int lcol = wn + j * 16 + lr;
                    float bv = bias[(n0 + lcol) & 63];
                    #pragma unroll
                    for (int rr = 0; rr < 4; ++rr) {
                        float v = fmaxf(acc[i][j][rr] + bv, 0.f);
                        Ct[(lrow + rr) * 136 + lcol] = f2bf(v);
                    }
                }
            }
        }
        __syncthreads();
        #pragma unroll
        for (int p = 0; p < 4; ++p) {
            int idx = p * 256 + tid;
            int row = idx >> 4, cg = idx & 15;
            *(uint4*)(C + (size_t)(m0 + h * 64 + row) * N + n0 + cg * 8) =
                *(const uint4*)(&Ct[row * 136 + cg * 8]);
        }
        __syncthreads();
    }
}

// ---------------- fused prep: im2col + all weight transforms ----------------
// seg0 im2col (6291456), seg1 wp (147456), seg2 wi (147456), seg3 wo (73728),
// seg4 W2 transpose (3145728), seg5 wconv (9216), seg6 wxd (159744).
__global__ __launch_bounds__(256) void prep_all(
    const float* __restrict__ x, unsigned short* __restrict__ P,
    const float* __restrict__ patch_w, unsigned short* __restrict__ wp,
    const float* __restrict__ in_proj_w, unsigned short* __restrict__ wi,
    const float* __restrict__ out_proj_w, unsigned short* __restrict__ wo,
    const float* __restrict__ deconv_w, unsigned short* __restrict__ W2,
    const float* __restrict__ dec_conv_w, unsigned short* __restrict__ wconv,
    const float* __restrict__ dtw, const float* __restrict__ xpw,
    unsigned short* __restrict__ wxd)
{
    int i = blockIdx.x * 256 + threadIdx.x;     // 9974784 total
    if (i < 6291456) {
        int col = i % 768, row = i / 768;
        int b = row >> 10, l = row & 1023;
        int h = l >> 5, w = l & 31;
        int c = col >> 8, p = (col >> 4) & 15, q = col & 15;
        P[i] = f2bf(x[((size_t)(b * 3 + c) * 512 + (h * 16 + p)) * 512 + (w * 16 + q)]);
        return;
    }
    i -= 6291456;
    if (i < 147456) { wp[i] = f2bf(patch_w[i]); return; }
    i -= 147456;
    if (i < 147456) { wi[i] = f2bf(in_proj_w[i]); return; }
    i -= 147456;
    if (i < 73728) { wo[i] = f2bf(out_proj_w[i]); return; }
    i -= 73728;
    if (i < 3145728) {                          // deconv_w -> W2[(p16+q)*64+k][c]
        int c = i % 192, np = i / 192;
        int k = np & 63, pq = np >> 6;
        W2[i] = f2bf(deconv_w[(size_t)c * 16384 + k * 256 + pq]);
        return;
    }
    i -= 3145728;
    if (i < 9216) {                             // dec_conv_w -> wconv[tap][m16][ch]
        int ch = i & 63, m = (i >> 6) & 15, tap = i >> 10;
        int dy = tap / 3, dx = tap % 3;
        float v = (m < 3) ? dec_conv_w[((m * 64 + ch) * 3 + dy) * 3 + dx] : 0.f;
        wconv[i] = f2bf(v);
        return;
    }
    i -= 9216;
    {                                           // wxd (416 x 384)
        int col = i % 384, row = i / 384;
        float v;
        if (row < 384) {
            v = 0.f;
            #pragma unroll
            for (int j = 0; j < 12; ++j)
                v = fmaf(dtw[row * 12 + j], xpw[j * 384 + col], v);
        } else {
            v = xpw[(row - 384 + 12) * 384 + col];
        }
        wxd[i] = f2bf(v);
    }
}

// ---------------- depthwise causal conv1d + silu (bf16 in, dual out) --------
__global__ __launch_bounds__(256) void conv1d_silu(const unsigned short* __restrict__ xz,
                                                   const float* __restrict__ cw,
                                                   const float* __restrict__ cb,
                                                   float* __restrict__ u32,
                                                   unsigned short* __restrict__ u16)
{
    int idx = blockIdx.x * 256 + threadIdx.x;   // 8192*384
    int d = idx % 384;
    int row = idx / 384;
    int l = row & 1023;
    float acc = cb[d];
    #pragma unroll
    for (int j = 0; j < 4; ++j) {
        int ll = l - 3 + j;
        if (ll >= 0) acc += bf2f(xz[(size_t)(row - 3 + j) * 768 + d]) * cw[d * 4 + j];
    }
    float s = acc / (1.f + __expf(-acc));
    u32[idx] = s;
    u16[idx] = f2bf(s);
}

// ---------------- selective scan, 3-pass: 32 chunks of 32 -------------------
__global__ __launch_bounds__(256) void ssm_pass1(const float* __restrict__ delta,
                                                 const float* __restrict__ bc,
                                                 const float* __restrict__ u,
                                                 const float* __restrict__ A_log,
                                                 float* __restrict__ Pc,
                                                 float* __restrict__ Hc)
{
    const int tid = threadIdx.x;
    const int n4 = tid & 3, dloc = tid >> 2;
    const int c = blockIdx.x, dg = blockIdx.y, b = blockIdx.z;
    const int d = dg * 64 + dloc;
    const int blk = (b * 6 + dg) * 32 + c;
    f32x4 A4 = *(const f32x4*)(A_log + d * 16 + n4 * 4);
    float Aa[4];
    #pragma unroll
    for (int j = 0; j < 4; ++j) Aa[j] = -__expf(A4[j]);
    const float* dp = delta + (size_t)(b * 1024) * 384 + d;
    const float* up = u     + (size_t)(b * 1024) * 384 + d;
    const float* bp = bc    + (size_t)(b * 1024) * 32;
    float P[4] = {1.f, 1.f, 1.f, 1.f}, H[4] = {0.f, 0.f, 0.f, 0.f};
    const int l0 = c * 32;
    for (int l = l0; l < l0 + 32; ++l) {
        float dlv = dp[(size_t)l * 384];
        float ulv = up[(size_t)l * 384];
        f32x4 B4 = *(const f32x4*)(bp + (size_t)l * 32 + n4 * 4);
        float du = dlv * ulv;
        #pragma unroll
        for (int j = 0; j < 4; ++j) {
            float a = __expf(dlv * Aa[j]);
            P[j] *= a;
            H[j] = fmaf(a, H[j], du * B4[j]);
        }
    }
    size_t o = ((size_t)blk * 256 + tid) * 4;
    *(f32x4*)(Pc + o) = (f32x4){P[0], P[1], P[2], P[3]};
    *(f32x4*)(Hc + o) = (f32x4){H[0], H[1], H[2], H[3]};
}

__global__ __launch_bounds__(256) void ssm_pass2(const float* __restrict__ Pc,
                                                 const float* __restrict__ Hc,
                                                 float* __restrict__ h0c)
{
    int t = blockIdx.x * 256 + threadIdx.x;    // 49152
    int grp = t >> 10, dn = t & 1023;
    float h = 0.f;
    #pragma unroll
    for (int c = 0; c < 32; ++c) {
        size_t idx = ((size_t)(grp * 32 + c)) * 1024 + dn;
        h0c[idx] = h;
        h = fmaf(Pc[idx], h, Hc[idx]);
    }
}

__global__ __launch_bounds__(256) void ssm_pass3(const float* __restrict__ delta,
                                                 const float* __restrict__ bc,
                                                 const float* __restrict__ u,
                                                 const unsigned short* __restrict__ xz,
                                                 const float* __restrict__ A_log,
                                                 const float* __restrict__ Dp,
                                                 const float* __restrict__ h0c,
                                                 unsigned short* __restrict__ y16)
{
    const int tid = threadIdx.x;
    const int n4 = tid & 3, dloc = tid >> 2;
    const int c = blockIdx.x, dg = blockIdx.y, b = blockIdx.z;
    const int d = dg * 64 + dloc;
    const int blk = (b * 6 + dg) * 32 + c;
    f32x4 A4 = *(const f32x4*)(A_log + d * 16 + n4 * 4);
    float Aa[4];
    #pragma unroll
    for (int j = 0; j < 4; ++j) Aa[j] = -__expf(A4[j]);
    float Dv = Dp[d];
    const float* dp = delta + (size_t)(b * 1024) * 384 + d;
    const float* up = u     + (size_t)(b * 1024) * 384 + d;
    const float* bp = bc    + (size_t)(b * 1024) * 32;
    const unsigned short* zp = xz + (size_t)(b * 1024) * 768 + 384 + d;
    unsigned short* yp = y16 + (size_t)(b * 1024) * 384 + d;
    f32x4 h4 = *(const f32x4*)(h0c + ((size_t)blk * 256 + tid) * 4);
    float H[4] = {h4[0], h4[1], h4[2], h4[3]};
    const int l0 = c * 32;
    for (int l = l0; l < l0 + 32; ++l) {
        float dlv = dp[(size_t)l * 384];
        float ulv = up[(size_t)l * 384];
        f32x4 B4 = *(const f32x4*)(bp + (size_t)l * 32 + n4 * 4);
        f32x4 C4 = *(const f32x4*)(bp + (size_t)l * 32 + 16 + n4 * 4);
        float du = dlv * ulv;
        float part = 0.f;
        #pragma unroll
        for (int j = 0; j < 4; ++j) {
            float a = __expf(dlv * Aa[j]);
            H[j] = fmaf(a, H[j], du * B4[j]);
            part = fmaf(H[j], C4[j], part);
        }
        part += __shfl_xor(part, 1, 4);
        part += __shfl_xor(part, 2, 4);
        if (n4 == 0) {
            float z = bf2f(zp[(size_t)l * 768]);
            float sz = z / (1.f + __expf(-z));
            yp[(size_t)l * 384] = f2bf((part + ulv * Dv) * sz);
        }
    }
}

// ---------------- MFMA 3x3 conv (64->3) + bias + sigmoid, G batches ---------
__global__ __launch_bounds__(256) void decconv_mfma(
    const unsigned short* __restrict__ Db, const unsigned short* __restrict__ wconv,
    const float* __restrict__ dcb, float* __restrict__ out, int base_b)
{
    __shared__ unsigned short ds[18 * 18 * 72];
    const int t = threadIdx.x;
    const int pidx = blockIdx.x;
    const int bb = blockIdx.y;
    const int b = base_b + bb;
    const unsigned short* Dbb = Db + (size_t)bb * 16777216;
    const int ph = pidx >> 5, pw = pidx & 31;
    const uint4 z4 = {0, 0, 0, 0};

    const unsigned short* base = Dbb + ((size_t)pidx << 14);
    #pragma unroll
    for (int s = 0; s < 8; ++s) {
        int f = s * 256 + t;
        int k8 = f & 7, pq = f >> 3;
        *(uint4*)&ds[(((pq >> 4) + 1) * 18 + (pq & 15) + 1) * 72 + k8 * 8] =
            *(const uint4*)(base + pq * 64 + k8 * 8);
    }
    {
        int k8 = t & 7, e = (t >> 3) & 15;
        if (t < 128) {
            uint4 v = z4;
            if (ph > 0) v = *(const uint4*)(Dbb + ((size_t)(pidx - 32) << 14) + (240 + e) * 64 + k8 * 8);
            *(uint4*)&ds[(0 * 18 + e + 1) * 72 + k8 * 8] = v;
        } else {
            uint4 v = z4;
            if (ph < 31) v = *(const uint4*)(Dbb + ((size_t)(pidx + 32) << 14) + e * 64 + k8 * 8);
            *(uint4*)&ds[(17 * 18 + e + 1) * 72 + k8 * 8] = v;
        }
        if (t < 128) {
            uint4 v = z4;
            if (pw > 0) v = *(const uint4*)(Dbb + ((size_t)(pidx - 1) << 14) + (e * 16 + 15) * 64 + k8 * 8);
            *(uint4*)&ds[((e + 1) * 18 + 0) * 72 + k8 * 8] = v;
        } else {
            uint4 v = z4;
            if (pw < 31) v = *(const uint4*)(Dbb + ((size_t)(pidx + 1) << 14) + (e * 16) * 64 + k8 * 8);
            *(uint4*)&ds[((e + 1) * 18 + 17) * 72 + k8 * 8] = v;
        }
        if (t < 32) {
            int c = t >> 3;
            int dh = (c >> 1) * 2 - 1, dw = (c & 1) * 2 - 1;
            int nh = ph + dh, nw = pw + dw;
            int sp = dh < 0 ? 15 : 0, sq = dw < 0 ? 15 : 0;
            uint4 v = z4;
            if (nh >= 0 && nh < 32 && nw >= 0 && nw < 32)
                v = *(const uint4*)(Dbb + ((size_t)(nh * 32 + nw) << 14) + (sp * 16 + sq) * 64 + k8 * 8);
            int dy = dh < 0 ? 0 : 17, dx = dw < 0 ? 0 : 17;
            *(uint4*)&ds[(dy * 18 + dx) * 72 + k8 * 8] = v;
        }
    }
    __syncthreads();

    const int wave = t >> 6, lane = t & 63;
    const int quad = lane >> 4, lr = lane & 15;
    f32x4 acc[4];
    #pragma unroll
    for (int i = 0; i < 4; ++i) acc[i] = (f32x4){0.f, 0.f, 0.f, 0.f};

    #pragma unroll
    for (int tap = 0; tap < 9; ++tap) {
        const int dy = tap / 3, dx = tap % 3;
        bf16x8 a0 = *(const bf16x8*)(wconv + (tap * 16 + lr) * 64 + quad * 8);
        bf16x8 a1 = *(const bf16x8*)(wconv + (tap * 16 + lr) * 64 + 32 + quad * 8);
        #pragma unroll
        for (int i = 0; i < 4; ++i) {
            int p = wave * 4 + i;
            const unsigned short* cell = &ds[((p + dy) * 18 + lr + dx) * 72];
            bf16x8 b0 = *(const bf16x8*)(cell + quad * 8);
            bf16x8 b1 = *(const bf16x8*)(cell + 32 + quad * 8);
            acc[i] = __builtin_amdgcn_mfma_f32_16x16x32_bf16(a0, b0, acc[i], 0, 0, 0);
            acc[i] = __builtin_amdgcn_mfma_f32_16x16x32_bf16(a1, b1, acc[i], 0, 0, 0);
        }
    }

    if (quad == 0) {
        float b0 = dcb[0], b1 = dcb[1], b2 = dcb[2];
        #pragma unroll
        for (int i = 0; i < 4; ++i) {
            int Y = ph * 16 + wave * 4 + i, X = pw * 16 + lr;
            size_t o = (size_t)(b * 3) * 262144 + (size_t)Y * 512 + X;
            out[o]          = 1.f / (1.f + __expf(-(acc[i][0] + b0)));
            out[o + 262144] = 1.f / (1.f + __expf(-(acc[i][1] + b1)));
            out[o + 524288] = 1.f / (1.f + __expf(-(acc[i][2] + b2)));
        }
    }
}

// ---------------------------------------------------------------------------
// Workspace (float units). Encoder scratch in [0, 15204352). Decoder Db at 0
// (G*4194304*G... G batches x 8388608 ushorts). Persistent weights above Db.
// big ws (>=143.2 MB): G=4, weights at 33554432; else G=2, weights at 16777216.
// ---------------------------------------------------------------------------
#define WS_P16      0            // bf16 8192x768 (1572864 f), dead after patch gemm
#define WS_DELTA    0            // f32 8192x384 (3145728 f)
#define WS_SEQ16    3145728      // bf16 (393216 f), dead after in_proj
#define WS_XZ16     3538944      // bf16 8192x768 (3145728 f) -> 6684672
#define WS_U32      6684672      // f32 (3145728 f) -> 9830400
#define WS_U16      9830400      // bf16 (393216 f) -> 10223616; y16 aliases after
#define WS_Y16      9830400
#define WS_BC       10223616     // f32 8192x32 (262144 f) -> 10485760
#define WS_PC       10485760     // -> 12058624
#define WS_HC       12058624     // -> 13631488
#define WS_H0C      13631488     // -> 15204352

extern "C" void kernel_launch(void* const* d_in, const int* in_sizes, int n_in,
                              void* d_out, int out_size, void* d_ws, size_t ws_size,
                              hipStream_t stream)
{
    const float* x         = (const float*)d_in[0];
    const float* patch_w   = (const float*)d_in[1];
    const float* patch_b   = (const float*)d_in[2];
    const float* in_proj_w = (const float*)d_in[3];
    const float* conv1d_w  = (const float*)d_in[4];
    const float* conv1d_b  = (const float*)d_in[5];
    const float* x_proj_w  = (const float*)d_in[6];
    const float* dt_proj_w = (const float*)d_in[7];
    const float* dt_proj_b = (const float*)d_in[8];
    const float* A_log     = (const float*)d_in[9];
    const float* Dp        = (const float*)d_in[10];
    const float* out_proj_w= (const float*)d_in[11];
    const float* deconv_w  = (const float*)d_in[12];
    const float* deconv_b  = (const float*)d_in[13];
    const float* dec_conv_w= (const float*)d_in[14];
    const float* dec_conv_b= (const float*)d_in[15];
    float* out = (float*)d_out;
    float* ws  = (float*)d_ws;

    // decoder group size: 4 batches if ws holds Db(4) + weights, else 2.
    const int G = (ws_size >= (size_t)143157248) ? 4 : 2;
    const size_t wbase = (G == 4) ? 33554432 : 16777216;   // floats

    unsigned short* P16   = (unsigned short*)(ws + WS_P16);
    float*          delta = ws + WS_DELTA;
    unsigned short* seq16 = (unsigned short*)(ws + WS_SEQ16);
    unsigned short* xz16  = (unsigned short*)(ws + WS_XZ16);
    float*          u32   = ws + WS_U32;
    unsigned short* u16   = (unsigned short*)(ws + WS_U16);
    unsigned short* y16   = (unsigned short*)(ws + WS_Y16);
    float*          bc    = ws + WS_BC;
    float*          Pc    = ws + WS_PC;
    float*          Hc    = ws + WS_HC;
    float*          h0c   = ws + WS_H0C;
    unsigned short* Db16  = (unsigned short*)(ws);
    unsigned short* seqo_b= (unsigned short*)(ws + wbase);
    unsigned short* W2b   = (unsigned short*)(ws + wbase + 393216);
    unsigned short* wconv = (unsigned short*)(ws + wbase + 1966080);
    unsigned short* wp16  = (unsigned short*)(ws + wbase + 1970688);
    unsigned short* wi16  = (unsigned short*)(ws + wbase + 2044416);
    unsigned short* wo16  = (unsigned short*)(ws + wbase + 2118144);
    unsigned short* wxd   = (unsigned short*)(ws + wbase + 2155008);

    // 1. fused prep: im2col + all weight transforms (incl. Wdt@Wx12 compose)
    prep_all<<<38964, 256, 0, stream>>>(x, P16, patch_w, wp16, in_proj_w, wi16,
                                        out_proj_w, wo16, deconv_w, W2b,
                                        dec_conv_w, wconv, dt_proj_w, x_proj_w, wxd);
    // 2. patch embedding -> seq16 bf16
    gemm_mfma_flex<<<dim3(2, 64), 256, 0, stream>>>(P16, wp16, seq16, patch_b,
                                                    8192, 192, 768, 1);
    // 3. in_proj -> xz16 bf16
    gemm_mfma_flex<<<dim3(6, 64), 256, 0, stream>>>(seq16, wi16, xz16, nullptr,
                                                    8192, 768, 192, 1);
    // 4. conv1d + silu -> u32 + u16
    conv1d_silu<<<12288, 256, 0, stream>>>(xz16, conv1d_w, conv1d_b, u32, u16);
    // 5. combined x_proj+dt_proj -> delta (softplus) + bc
    gemm_xd<<<dim3(4, 64), 256, 0, stream>>>(u16, wxd, delta, bc, dt_proj_b);
    // 6. selective scan (3-pass, 32 chunks of 32)
    ssm_pass1<<<dim3(32, 6, 8), 256, 0, stream>>>(delta, bc, u32, A_log, Pc, Hc);
    ssm_pass2<<<192, 256, 0, stream>>>(Pc, Hc, h0c);
    ssm_pass3<<<dim3(32, 6, 8), 256, 0, stream>>>(delta, bc, u32, xz16, A_log, Dp, h0c, y16);
    // 7. out_proj -> seqo_b bf16
    gemm_mfma_flex<<<dim3(2, 64), 256, 0, stream>>>(y16, wo16, seqo_b, nullptr,
                                                    8192, 192, 384, 1);
    // 8. decoder: 8/G groups x (G-batch MFMA GEMM -> G-batch MFMA conv+sigmoid)
    for (int g = 0; g < 8 / G; ++g) {
        gemm_mfma_relu_bf16<<<dim3(128, 8, G), 256, 0, stream>>>(
            seqo_b, W2b, Db16, deconv_b, g * G);
        decconv_mfma<<<dim3(1024, G), 256, 0, stream>>>(Db16, wconv, dec_conv_b, out, g * G);
    }
}